// Round 7
// baseline (403.866 us; speedup 1.0000x reference)
//
#include <hip/hip_runtime.h>
#include <hip/hip_bf16.h>
#include <math.h>

// Shapes
#define NN 64
#define CC 64
#define TT 256
#define VV 25
#define DD 64
#define BN_EPS 1e-5f
#define NREP 16

typedef short bf16x8 __attribute__((ext_vector_type(8)));
typedef float f32x4 __attribute__((ext_vector_type(4)));

// ws layout (float offsets)
#define WS_POOLED 0            // [64][64]
#define WS_GATE   4096         // [64][4]
#define WS_BFUSE  4352         // [64][64]
#define WS_MASK   8448         // [25][64] f32
#define WS_ABP    10048        // u32[1600] packed bf16 (a=lo16, b=hi16)
#define WS_S1     13248        // [16][1600] replicas (memset 0)
#define WS_S2     38848        // [16][1600]
#define WS_WTB    64448        // ushort[64][64][64] fused W^T bf16

static __device__ __forceinline__ unsigned short f2bf(float x) {
    __hip_bfloat16 h = __float2bfloat16(x);
    return *(unsigned short*)&h;
}
static __device__ __forceinline__ float bf2f(unsigned short u) {
    return __uint_as_float(((unsigned)u) << 16);
}

// ---------------- K0: global average pool over (T,V) ----------------
__global__ __launch_bounds__(256) void k_pool(const float* __restrict__ x0,
                                              float* __restrict__ pooled) {
    __shared__ float red[256];
    const int bid = blockIdx.x;                // n*64 + c
    const float4* p = (const float4*)(x0 + (size_t)bid * (TT * VV));
    float4 xv[7];
#pragma unroll
    for (int it = 0; it < 7; it++) {
        const int k = threadIdx.x + it * 256;
        if (k < 1600) xv[it] = p[k];
    }
    float s = 0.f;
#pragma unroll
    for (int it = 0; it < 7; it++) {
        const int k = threadIdx.x + it * 256;
        if (k < 1600) s += xv[it].x + xv[it].y + xv[it].z + xv[it].w;
    }
    red[threadIdx.x] = s;
    __syncthreads();
    for (int off = 128; off > 0; off >>= 1) {
        if (threadIdx.x < off) red[threadIdx.x] += red[threadIdx.x + off];
        __syncthreads();
    }
    if (threadIdx.x == 0) pooled[bid] = red[0] * (1.f / (TT * VV));
}

// ---------------- K1: gate MLP + softmax, bfuse, mask ----------------
__global__ __launch_bounds__(256) void k_gate(const float* __restrict__ fc1_w,
                                              const float* __restrict__ fc1_b,
                                              const float* __restrict__ fc2_w,
                                              const float* __restrict__ fc2_b,
                                              const float* __restrict__ lin_b,
                                              const float* __restrict__ fmask,
                                              const int* __restrict__ epoch_p,
                                              float* ws) {
    const int tid = threadIdx.x;
    float* pooled = ws + WS_POOLED;
    float* gate   = ws + WS_GATE;
    float* bfuse  = ws + WS_BFUSE;
    float* mask   = ws + WS_MASK;

    if (tid < 64) {
        const int n = tid;
        const float* po = pooled + n * 64;
        float h[16];
        for (int q = 0; q < 16; q++) {
            float z = fc1_b[q];
            for (int j = 0; j < 64; j++) z = fmaf(fc1_w[q * 64 + j], po[j], z);
            h[q] = fmaxf(z, 0.f);
        }
        float lg[4];
        for (int k = 0; k < 4; k++) {
            float z = fc2_b[k];
            for (int q = 0; q < 16; q++) z = fmaf(fc2_w[k * 16 + q], h[q], z);
            lg[k] = z;
        }
        const int ep = epoch_p[0];
        const float tao = (ep < 60) ? (-(29.0f / 60.0f) * (float)ep + 30.0f) : 1.0f;
        float mx = -1e30f;
        for (int k = 0; k < 4; k++) { lg[k] /= tao; mx = fmaxf(mx, lg[k]); }
        float se = 0.f;
        for (int k = 0; k < 4; k++) { lg[k] = expf(lg[k] - mx); se += lg[k]; }
        const float inv = 1.f / se;
        for (int k = 0; k < 4; k++) gate[n * 4 + k] = lg[k] * inv;
    }
    __syncthreads();
    for (int f = tid; f < 4096; f += 256) {
        const int n = f >> 6, d = f & 63;
        float s = 0.f;
        for (int k = 0; k < 4; k++) s = fmaf(lin_b[k * 64 + d], gate[n * 4 + k], s);
        bfuse[f] = s;
    }
    for (int f = tid; f < VV * CC; f += 256) mask[f] = tanhf(fmask[f]) + 1.0f;
}

// ---------------- K1b: fused weight, transposed, bf16: Wtb[n][d][c] ----------------
__global__ __launch_bounds__(256) void k_wfuse(const float* __restrict__ lw, float* ws) {
    __shared__ float tile[64 * 65];
    const float* gate = ws + WS_GATE;
    unsigned short* wtb = (unsigned short*)(ws + WS_WTB);
    const int n = blockIdx.x;
    float g[4];
    for (int k = 0; k < 4; k++) g[k] = gate[n * 4 + k];
    for (int f = threadIdx.x; f < 4096; f += 256) {
        const int c = f >> 6, d = f & 63;
        float v = g[0] * lw[f] + g[1] * lw[4096 + f] + g[2] * lw[8192 + f] + g[3] * lw[12288 + f];
        tile[d * 65 + c] = v;
    }
    __syncthreads();
    for (int f = threadIdx.x; f < 4096; f += 256) {
        const int d = f >> 6, c = f & 63;
        wtb[n * 4096 + f] = f2bf(tile[d * 65 + c]);
    }
}

// ---------------- K3: finalize BN -> packed bf16 (scale, shift) ----------------
__global__ __launch_bounds__(256) void k_finalize(const float* __restrict__ gamma,
                                                  const float* __restrict__ beta,
                                                  float* ws) {
    const int f = blockIdx.x * 256 + threadIdx.x;   // out-feature v*64+d
    if (f >= VV * DD) return;
    const int v = f >> 6, d = f & 63;
    const int vi = (v - d + 175) % 25;              // source (unshifted) v index
    const int fin = vi * 64 + d;
    float s1 = 0.f, s2 = 0.f;
    for (int rep = 0; rep < NREP; rep++) {
        s1 += ws[WS_S1 + rep * 1600 + fin];
        s2 += ws[WS_S2 + rep * 1600 + fin];
    }
    const float mean = s1 * (1.f / (NN * TT));
    float var = s2 * (1.f / (NN * TT)) - mean * mean;
    var = fmaxf(var, 0.f);
    const float rs = rsqrtf(var + BN_EPS);
    const float a = gamma[f] * rs;
    const float b = beta[f] - mean * a;
    ((unsigned*)ws)[WS_ABP + f] = (unsigned)f2bf(a) | (((unsigned)f2bf(b)) << 16);
}

// ---------------- K2/K4: main per-sample GEMM via bf16 MFMA (LDS-staged) ----------------
// PHASE 0: grid (16,64), 4 chunks; stats in registers -> LDS reduce -> replica atomics.
// PHASE 1: grid (32,64), 2 chunks; BN + shift-out into bf16 outl (aliased in Xm) -> coalesced
//          float4 store with residual + relu.
// All 6.25-trip strided loops statically unrolled (7 iters, predicated) so the 7
// global loads issue back-to-back instead of serializing one latency each.
template <int PHASE>
__global__ __launch_bounds__(256, 4) void k_main(const float* __restrict__ x0,
                                                 const unsigned short* __restrict__ wtb,
                                                 const float* __restrict__ ws,
                                                 float* __restrict__ wsmut,
                                                 float* __restrict__ out) {
    constexpr int LDSZ = (PHASE == 0) ? 31856 : 38656;
    __shared__ __align__(16) char pool[LDSZ];
    unsigned short (*Wl)[72] = (unsigned short(*)[72])(pool);          // 9216 B
    float* maskL = (float*)(pool + 9216);                              // [25][65] 6500 B
    unsigned short (*Xm)[72] = (unsigned short(*)[72])(pool + 15728);  // [112][72] 16128 B
    unsigned* ABl = (unsigned*)(pool + 31856);                         // P1 only: [25][68] u32
    unsigned short* outl = (unsigned short*)(pool + 15728);            // P1: [64][104] bf16, aliases Xm

    const int n = blockIdx.y, tb = blockIdx.x;
    const int tid = threadIdx.x;
    const int wv = tid >> 6, lane = tid & 63;
    const int lrow = lane & 15, lgrp = lane >> 4;
    const int dcol = wv * 16 + lrow;
    constexpr int NCK = (PHASE == 0) ? 4 : 2;
    const int colbase = tb * 100 * NCK;

    // ---- one-time staging ----
    {
        const uint4* wsrc = (const uint4*)(wtb + n * 4096);
#pragma unroll
        for (int it = 0; it < 2; it++) {
            const int itx = tid + it * 256;
            uint4 u = wsrc[itx];
            const int f8 = itx * 8;
            *(uint4*)&Wl[f8 >> 6][f8 & 63] = u;
        }
        for (int f = tid; f < 1600; f += 256)
            maskL[(f >> 6) * 65 + (f & 63)] = ws[WS_MASK + f];
        // zero Xm pad rows 100..111 (read by MFMA, results discarded; never clobbered)
        for (int f = tid; f < 864; f += 256) ((unsigned short*)Xm)[7200 + f] = 0;
        if (PHASE == 1) {
            const unsigned* abp = (const unsigned*)(ws + WS_ABP);
            for (int f = tid; f < 1600; f += 256)
                ABl[(f >> 6) * 68 + (f & 63)] = abp[f];
        }
    }
    const float bfv = ws[WS_BFUSE + n * 64 + dcol];
    __syncthreads();

    const bf16x8 w0 = *(const bf16x8*)&Wl[dcol][8 * lgrp];
    const bf16x8 w1 = *(const bf16x8*)&Wl[dcol][32 + 8 * lgrp];

    float s1r[7][4], s2r[7][4];
    if (PHASE == 0) {
#pragma unroll
        for (int m = 0; m < 7; m++)
#pragma unroll
            for (int r = 0; r < 4; r++) { s1r[m][r] = 0.f; s2r[m][r] = 0.f; }
    }

    const size_t nbase = (size_t)n * (CC * TT * VV);

    for (int ck = 0; ck < NCK; ck++) {
        const int gcol0 = colbase + ck * 100;
        if (ck) __syncthreads();      // prior chunk fully consumed (MFMA reads / outl flush)

        // ---- stage X chunk: issue ALL 7 float4 loads, then gather+mask+convert ----
        float4 xv[7];
#pragma unroll
        for (int it = 0; it < 7; it++) {
            const int l4 = tid + it * 256;
            if (l4 < 1600) {
                const int j = l4 / 25, q = l4 - j * 25;
                xv[it] = *(const float4*)(x0 + nbase + j * 6400 + gcol0 + q * 4);
            }
        }
#pragma unroll
        for (int it = 0; it < 7; it++) {
            const int l4 = tid + it * 256;
            if (l4 < 1600) {
                const int j = l4 / 25, q = l4 - j * 25;
                int jm = j; if (jm >= 50) jm -= 50; else if (jm >= 25) jm -= 25;
                const float xe[4] = {xv[it].x, xv[it].y, xv[it].z, xv[it].w};
#pragma unroll
                for (int e = 0; e < 4; e++) {
                    const int r = q * 4 + e;
                    const int trel = (r >= 75) ? 3 : (r >= 50) ? 2 : (r >= 25) ? 1 : 0;
                    const int p = r - trel * 25;
                    int i = p - jm; if (i < 0) i += 25;
                    Xm[trel * 25 + i][j] = f2bf(xe[e] * maskL[i * 65 + j]);
                }
            }
        }
        __syncthreads();

        // ---- MFMA: A = Xm rows (tv), B = W rows (d); acc rows = tv, cols = d ----
        f32x4 acc[7];
#pragma unroll
        for (int m = 0; m < 7; m++) {
            f32x4 a = {bfv, bfv, bfv, bfv};
            const bf16x8 a0 = *(const bf16x8*)&Xm[m * 16 + lrow][8 * lgrp];
            const bf16x8 a1 = *(const bf16x8*)&Xm[m * 16 + lrow][32 + 8 * lgrp];
            a = __builtin_amdgcn_mfma_f32_16x16x32_bf16(a0, w0, a, 0, 0, 0);
            a = __builtin_amdgcn_mfma_f32_16x16x32_bf16(a1, w1, a, 0, 0, 0);
            acc[m] = a;
        }

        if (PHASE == 0) {
#pragma unroll
            for (int m = 0; m < 7; m++) {
#pragma unroll
                for (int r = 0; r < 4; r++) {
                    const int row = m * 16 + 4 * lgrp + r;
                    if (row < 100) {
                        const float y = acc[m][r];
                        s1r[m][r] += y;
                        s2r[m][r] = fmaf(y, y, s2r[m][r]);
                    }
                }
            }
        } else {
            __syncthreads();   // all waves done reading shared Xm fragments before outl overwrite
            // BN + shift-out into bf16 outl[d][trel*25+vo]
#pragma unroll
            for (int m = 0; m < 7; m++) {
#pragma unroll
                for (int r = 0; r < 4; r++) {
                    const int row = m * 16 + 4 * lgrp + r;
                    if (row < 100) {
                        const int trel = (row >= 75) ? 3 : (row >= 50) ? 2 : (row >= 25) ? 1 : 0;
                        const int v = row - trel * 25;
                        int vo = v + dcol;
                        if (vo >= 75) vo -= 75; else if (vo >= 50) vo -= 50; else if (vo >= 25) vo -= 25;
                        const unsigned u = ABl[vo * 68 + dcol];
                        const float a_ = __uint_as_float(u << 16);
                        const float b_ = __uint_as_float(u & 0xffff0000u);
                        outl[dcol * 104 + trel * 25 + vo] = f2bf(fmaf(a_, acc[m][r], b_));
                    }
                }
            }
            __syncthreads();
            // coalesced flush + residual + relu: prefetch x0 + outl, then compute/store
            float4 xr[7];
            uint2 uy[7];
#pragma unroll
            for (int it = 0; it < 7; it++) {
                const int l4 = tid + it * 256;
                if (l4 < 1600) {
                    const int dd = l4 / 25, q = l4 - dd * 25;
                    xr[it] = *(const float4*)(x0 + nbase + dd * 6400 + gcol0 + q * 4);
                    uy[it] = *(const uint2*)(outl + dd * 104 + 4 * q);
                }
            }
#pragma unroll
            for (int it = 0; it < 7; it++) {
                const int l4 = tid + it * 256;
                if (l4 < 1600) {
                    const int dd = l4 / 25, q = l4 - dd * 25;
                    float4 o;
                    o.x = fmaxf(bf2f((unsigned short)(uy[it].x & 0xffff)) + xr[it].x, 0.f);
                    o.y = fmaxf(bf2f((unsigned short)(uy[it].x >> 16)) + xr[it].y, 0.f);
                    o.z = fmaxf(bf2f((unsigned short)(uy[it].y & 0xffff)) + xr[it].z, 0.f);
                    o.w = fmaxf(bf2f((unsigned short)(uy[it].y >> 16)) + xr[it].w, 0.f);
                    *(float4*)(out + nbase + dd * 6400 + gcol0 + q * 4) = o;
                }
            }
        }
    }

    if (PHASE == 0) {
        __syncthreads();                          // Xm dead; reuse as stats
        float* s1l = (float*)(pool + 15728);      // [25][66]
        float* s2l = s1l + 1650;
        for (int f = tid; f < 3300; f += 256) s1l[f] = 0.f;
        __syncthreads();
#pragma unroll
        for (int m = 0; m < 7; m++) {
#pragma unroll
            for (int r = 0; r < 4; r++) {
                const int row = m * 16 + 4 * lgrp + r;
                if (row < 100) {
                    int v = row;
                    if (v >= 75) v -= 75; else if (v >= 50) v -= 50; else if (v >= 25) v -= 25;
                    __hip_atomic_fetch_add(&s1l[v * 66 + dcol], s1r[m][r],
                                           __ATOMIC_RELAXED, __HIP_MEMORY_SCOPE_WORKGROUP);
                    __hip_atomic_fetch_add(&s2l[v * 66 + dcol], s2r[m][r],
                                           __ATOMIC_RELAXED, __HIP_MEMORY_SCOPE_WORKGROUP);
                }
            }
        }
        __syncthreads();
        const int rep = (n * 5 + tb) & (NREP - 1);
        float* g1 = wsmut + WS_S1 + rep * 1600;
        float* g2 = wsmut + WS_S2 + rep * 1600;
        for (int f = tid; f < 1600; f += 256) {
            atomicAdd(&g1[f], s1l[(f >> 6) * 66 + (f & 63)]);
            atomicAdd(&g2[f], s2l[(f >> 6) * 66 + (f & 63)]);
        }
    }
}

extern "C" void kernel_launch(void* const* d_in, const int* in_sizes, int n_in,
                              void* d_out, int out_size, void* d_ws, size_t ws_size,
                              hipStream_t stream) {
    const float* x0    = (const float*)d_in[0];
    const float* fc1_w = (const float*)d_in[1];
    const float* fc1_b = (const float*)d_in[2];
    const float* fc2_w = (const float*)d_in[3];
    const float* fc2_b = (const float*)d_in[4];
    const float* lw    = (const float*)d_in[5];
    const float* lb    = (const float*)d_in[6];
    const float* fmask = (const float*)d_in[7];
    const float* gamma = (const float*)d_in[8];
    const float* beta  = (const float*)d_in[9];
    const int* epoch   = (const int*)d_in[12];
    float* ws  = (float*)d_ws;
    float* out = (float*)d_out;
    const unsigned short* wtb = (const unsigned short*)(ws + WS_WTB);

    hipMemsetAsync((char*)d_ws + WS_S1 * sizeof(float), 0, (size_t)NREP * 3200 * sizeof(float), stream);
    k_pool<<<NN * CC, 256, 0, stream>>>(x0, ws + WS_POOLED);
    k_gate<<<1, 256, 0, stream>>>(fc1_w, fc1_b, fc2_w, fc2_b, lb, fmask, epoch, ws);
    k_wfuse<<<NN, 256, 0, stream>>>(lw, ws);

    k_main<0><<<dim3(16, 64), 256, 0, stream>>>(x0, wtb, ws, ws, out);
    k_finalize<<<7, 256, 0, stream>>>(gamma, beta, ws);
    k_main<1><<<dim3(32, 64), 256, 0, stream>>>(x0, wtb, ws, ws, out);
}

// Round 8
// 211.698 us; speedup vs baseline: 1.9077x; 1.9077x over previous
//
#include <hip/hip_runtime.h>
#include <hip/hip_bf16.h>
#include <math.h>

// Shapes
#define NN 64
#define CC 64
#define TT 256
#define VV 25
#define DD 64
#define BN_EPS 1e-5f
#define NREP 16

typedef short bf16x8 __attribute__((ext_vector_type(8)));
typedef float f32x4 __attribute__((ext_vector_type(4)));

// ws layout (float offsets)
#define WS_POOLED 0            // [64][64]  (atomic-accumulated means; memset 0)
#define WS_GATE   4096         // [64][4]
#define WS_BFUSE  4352         // [64][64]
#define WS_MASK   8448         // [25][64] f32
#define WS_ABP    10048        // u32[1600] packed bf16 (a=lo16, b=hi16)
#define WS_S1     13248        // [16][1600] replicas (memset 0)
#define WS_S2     38848        // [16][1600]
#define WS_WTB    64448        // ushort[64][64][64] fused W^T bf16
#define WS_YB     195520       // ushort[64][64][6400] y bf16

static __device__ __forceinline__ unsigned short f2bf(float x) {
    __hip_bfloat16 h = __float2bfloat16(x);
    return *(unsigned short*)&h;
}
static __device__ __forceinline__ float bf2f(unsigned short u) {
    return __uint_as_float(((unsigned)u) << 16);
}
// async global->LDS, 16B per lane; dest = wave-uniform base + lane*16 (linear)
static __device__ __forceinline__ void gload_lds16(const void* gsrc, void* ldst) {
    typedef const __attribute__((address_space(1))) unsigned int gu32;
    typedef __attribute__((address_space(3))) unsigned int lu32;
    __builtin_amdgcn_global_load_lds((gu32*)gsrc, (lu32*)ldst, 16, 0, 0);
}

// ---------------- K_mask: mask = tanh(FM)+1 ----------------
__global__ __launch_bounds__(256) void k_mask(const float* __restrict__ fmask, float* ws) {
    const int f = blockIdx.x * 256 + threadIdx.x;
    if (f < VV * CC) ws[WS_MASK + f] = tanhf(fmask[f]) + 1.0f;
}

// ---------------- K_xt: x0 -> xT[n][tv][c] bf16 (shift-in + mask, SWIZZLED), + pooling ----------------
// grid (64 tcb, 64 n). Swizzle: 16B granule g within a 128B row stored at g ^ (grow & 7).
__global__ __launch_bounds__(256) void k_xt(const float* __restrict__ x0,
                                            const float* __restrict__ ws,
                                            float* __restrict__ pooled,
                                            unsigned short* __restrict__ xT) {
    __shared__ __align__(16) float tile[64][104];   // [c][col], 26624 B
    const int n = blockIdx.y, tcb = blockIdx.x;
    const int tid = threadIdx.x;
    const size_t nbase = (size_t)n * (CC * TT * VV);
    const int col0 = tcb * 100;

    for (int l4 = tid; l4 < 1600; l4 += 256) {
        const int c = l4 / 25, q = l4 - c * 25;
        const float4 v = *(const float4*)(x0 + nbase + c * 6400 + col0 + 4 * q);
        *(float4*)&tile[c][4 * q] = v;
    }
    __syncthreads();

    if (tid < 64) {
        float s = 0.f;
        for (int q = 0; q < 25; q++) {
            const float4 v = *(const float4*)&tile[tid][4 * q];
            s += v.x + v.y + v.z + v.w;
        }
        atomicAdd(&pooled[n * 64 + tid], s * (1.f / 6400.f));
    }

    const float* maskg = ws + WS_MASK;
    for (int l = tid; l < 800; l += 256) {
        const int row = l >> 3;                  // 0..99
        const int jb = (l & 7) * 8;
        const int trel = row / 25, i = row - trel * 25;
        const float4 m0 = *(const float4*)(maskg + i * 64 + jb);
        const float4 m1 = *(const float4*)(maskg + i * 64 + jb + 4);
        const float mk[8] = {m0.x, m0.y, m0.z, m0.w, m1.x, m1.y, m1.z, m1.w};
        unsigned outw[4];
#pragma unroll
        for (int pair = 0; pair < 4; pair++) {
            unsigned lo = 0, hi = 0;
#pragma unroll
            for (int hl = 0; hl < 2; hl++) {
                const int j = jb + pair * 2 + hl;
                int jm = j; if (jm >= 50) jm -= 50; else if (jm >= 25) jm -= 25;
                int p = i + jm; if (p >= 25) p -= 25;
                const float v = tile[j][trel * 25 + p] * mk[pair * 2 + hl];
                if (hl == 0) lo = (unsigned)f2bf(v); else hi = (unsigned)f2bf(v);
            }
            outw[pair] = lo | (hi << 16);
        }
        const int grow = col0 + row;
        const int jswz = ((l & 7) ^ (grow & 7)) * 8;     // swizzled 16B granule
        *(uint4*)(xT + ((size_t)(n * 6400) + grow) * 64 + jswz) = *(uint4*)outw;
    }
}

// ---------------- K1: gate MLP + softmax, bfuse ----------------
__global__ __launch_bounds__(256) void k_gate(const float* __restrict__ fc1_w,
                                              const float* __restrict__ fc1_b,
                                              const float* __restrict__ fc2_w,
                                              const float* __restrict__ fc2_b,
                                              const float* __restrict__ lin_b,
                                              const int* __restrict__ epoch_p,
                                              float* ws) {
    const int tid = threadIdx.x;
    float* pooled = ws + WS_POOLED;
    float* gate   = ws + WS_GATE;
    float* bfuse  = ws + WS_BFUSE;

    if (tid < 64) {
        const int n = tid;
        const float* po = pooled + n * 64;
        float h[16];
        for (int q = 0; q < 16; q++) {
            float z = fc1_b[q];
            for (int j = 0; j < 64; j++) z = fmaf(fc1_w[q * 64 + j], po[j], z);
            h[q] = fmaxf(z, 0.f);
        }
        float lg[4];
        for (int k = 0; k < 4; k++) {
            float z = fc2_b[k];
            for (int q = 0; q < 16; q++) z = fmaf(fc2_w[k * 16 + q], h[q], z);
            lg[k] = z;
        }
        const int ep = epoch_p[0];
        const float tao = (ep < 60) ? (-(29.0f / 60.0f) * (float)ep + 30.0f) : 1.0f;
        float mx = -1e30f;
        for (int k = 0; k < 4; k++) { lg[k] /= tao; mx = fmaxf(mx, lg[k]); }
        float se = 0.f;
        for (int k = 0; k < 4; k++) { lg[k] = expf(lg[k] - mx); se += lg[k]; }
        const float inv = 1.f / se;
        for (int k = 0; k < 4; k++) gate[n * 4 + k] = lg[k] * inv;
    }
    __syncthreads();
    for (int f = tid; f < 4096; f += 256) {
        const int n = f >> 6, d = f & 63;
        float s = 0.f;
        for (int k = 0; k < 4; k++) s = fmaf(lin_b[k * 64 + d], gate[n * 4 + k], s);
        bfuse[f] = s;
    }
}

// ---------------- K1b: fused weight, transposed, bf16: Wtb[n][d][c] ----------------
__global__ __launch_bounds__(256) void k_wfuse(const float* __restrict__ lw, float* ws) {
    __shared__ float tile[64 * 65];
    const float* gate = ws + WS_GATE;
    unsigned short* wtb = (unsigned short*)(ws + WS_WTB);
    const int n = blockIdx.x;
    float g[4];
    for (int k = 0; k < 4; k++) g[k] = gate[n * 4 + k];
    for (int f = threadIdx.x; f < 4096; f += 256) {
        const int c = f >> 6, d = f & 63;
        float v = g[0] * lw[f] + g[1] * lw[4096 + f] + g[2] * lw[8192 + f] + g[3] * lw[12288 + f];
        tile[d * 65 + c] = v;
    }
    __syncthreads();
    for (int f = threadIdx.x; f < 4096; f += 256) {
        const int d = f >> 6, c = f & 63;
        wtb[n * 4096 + f] = f2bf(tile[d * 65 + c]);
    }
}

// ---------------- K_gemm: y = xT @ W^T + bias (bf16) + BN stats ----------------
// grid (16 tb, 64 n), 4 chunks of 100 rows. Xm staged by async global_load_lds
// (linear dest; swizzle pre-applied in xT). Next chunk's DMA overlaps this chunk's flush.
__global__ __launch_bounds__(256, 4) void k_gemm(const unsigned short* __restrict__ xT,
                                                 const unsigned short* __restrict__ wtb,
                                                 const float* __restrict__ ws,
                                                 float* __restrict__ wsmut) {
    __shared__ __align__(16) char pool[36352];
    unsigned short (*Wl)[72] = (unsigned short(*)[72])(pool);      // 9216 B
    unsigned short* Xm = (unsigned short*)(pool + 9216);           // [112][64] bf16 linear, 14336 B
    unsigned short* outl = (unsigned short*)(pool + 23552);        // [64][100] bf16, 12800 B

    const int n = blockIdx.y, tb = blockIdx.x;
    const int tid = threadIdx.x;
    const int wv = tid >> 6, lane = tid & 63;
    const int lrow = lane & 15, lgrp = lane >> 4;
    const int dcol = wv * 16 + lrow;

    {   // stage W once
        const uint4* wsrc = (const uint4*)(wtb + n * 4096);
#pragma unroll
        for (int it = 0; it < 2; it++) {
            const int itx = tid + it * 256;
            uint4 u = wsrc[itx];
            const int f8 = itx * 8;
            *(uint4*)&Wl[f8 >> 6][f8 & 63] = u;
        }
    }
    const float bfv = ws[WS_BFUSE + n * 64 + dcol];

    // issue chunk 0 DMA (14336 B; full-wave exec for every issued instr)
    {
        const char* xc = (const char*)(xT + ((size_t)n * 6400 + tb * 400) * 64);
#pragma unroll
        for (int it = 0; it < 4; it++) {
            const int off = it * 4096 + tid * 16;
            if (off < 14336) gload_lds16(xc + off, (char*)Xm + off);
        }
    }
    __syncthreads();                 // W staged (ds_writes drained)
    const bf16x8 w0 = *(const bf16x8*)&Wl[dcol][8 * lgrp];
    const bf16x8 w1 = *(const bf16x8*)&Wl[dcol][32 + 8 * lgrp];

    float s1r[7][4], s2r[7][4];
#pragma unroll
    for (int m = 0; m < 7; m++)
#pragma unroll
        for (int r = 0; r < 4; r++) { s1r[m][r] = 0.f; s2r[m][r] = 0.f; }

    unsigned short* yg = (unsigned short*)(wsmut + WS_YB) + (size_t)n * 64 * 6400;

    for (int ck = 0; ck < 4; ck++) {
        const int rowt = tb * 400 + ck * 100;
        asm volatile("s_waitcnt vmcnt(0)" ::: "memory");   // chunk DMA complete
        __syncthreads();                                   // + prev flush's outl reads done

        const int b7 = rowt & 7;
#pragma unroll
        for (int m = 0; m < 7; m++) {
            const int rloc = m * 16 + lrow;
            const int r7 = (rloc + b7) & 7;
            const bf16x8 a0 = *(const bf16x8*)(Xm + rloc * 64 + ((lgrp ^ r7) << 3));
            const bf16x8 a1 = *(const bf16x8*)(Xm + rloc * 64 + (((lgrp + 4) ^ r7) << 3));
            f32x4 a = {bfv, bfv, bfv, bfv};
            a = __builtin_amdgcn_mfma_f32_16x16x32_bf16(a0, w0, a, 0, 0, 0);
            a = __builtin_amdgcn_mfma_f32_16x16x32_bf16(a1, w1, a, 0, 0, 0);
#pragma unroll
            for (int r = 0; r < 4; r++) {
                const int row = m * 16 + 4 * lgrp + r;
                if (row < 100) {
                    const unsigned short us = f2bf(a[r]);
                    const float yf = bf2f(us);
                    s1r[m][r] += yf;
                    s2r[m][r] = fmaf(yf, yf, s2r[m][r]);
                    outl[dcol * 100 + row] = us;
                }
            }
        }
        __syncthreads();             // Xm reads + outl writes complete

        if (ck < 3) {                // overlap next DMA with flush
            const char* xc = (const char*)(xT + ((size_t)n * 6400 + rowt + 100) * 64);
#pragma unroll
            for (int it = 0; it < 4; it++) {
                const int off = it * 4096 + tid * 16;
                if (off < 14336) gload_lds16(xc + off, (char*)Xm + off);
            }
        }
        // flush outl -> y[n][d][rowt..rowt+99] (uint2 = 4 bf16, coalesced)
        for (int l = tid; l < 1600; l += 256) {
            const int dd = l / 25, q = l - dd * 25;
            const uint2 u = *(const uint2*)(outl + dd * 100 + 4 * q);
            *(uint2*)(yg + (size_t)dd * 6400 + rowt + 4 * q) = u;
        }
    }

    // stats: LDS reduce (alias Xm region), then one global atomic per feature
    float* s1l = (float*)Xm;                 // [25][66]
    float* s2l = s1l + 1650;
    for (int f = tid; f < 3300; f += 256) s1l[f] = 0.f;
    __syncthreads();
#pragma unroll
    for (int m = 0; m < 7; m++) {
#pragma unroll
        for (int r = 0; r < 4; r++) {
            const int row = m * 16 + 4 * lgrp + r;
            if (row < 100) {
                int v = row;
                if (v >= 75) v -= 75; else if (v >= 50) v -= 50; else if (v >= 25) v -= 25;
                __hip_atomic_fetch_add(&s1l[v * 66 + dcol], s1r[m][r],
                                       __ATOMIC_RELAXED, __HIP_MEMORY_SCOPE_WORKGROUP);
                __hip_atomic_fetch_add(&s2l[v * 66 + dcol], s2r[m][r],
                                       __ATOMIC_RELAXED, __HIP_MEMORY_SCOPE_WORKGROUP);
            }
        }
    }
    __syncthreads();
    const int rep = (n * 5 + tb) & (NREP - 1);
    float* g1 = wsmut + WS_S1 + rep * 1600;
    float* g2 = wsmut + WS_S2 + rep * 1600;
    for (int f = tid; f < 1600; f += 256) {
        atomicAdd(&g1[f], s1l[(f >> 6) * 66 + (f & 63)]);
        atomicAdd(&g2[f], s2l[(f >> 6) * 66 + (f & 63)]);
    }
}

// ---------------- K3: finalize BN -> packed bf16 (scale, shift) ----------------
__global__ __launch_bounds__(256) void k_finalize(const float* __restrict__ gamma,
                                                  const float* __restrict__ beta,
                                                  float* ws) {
    const int f = blockIdx.x * 256 + threadIdx.x;   // out-feature v*64+d
    if (f >= VV * DD) return;
    const int v = f >> 6, d = f & 63;
    const int vi = (v - d + 175) % 25;              // source (unshifted) v index
    const int fin = vi * 64 + d;
    float s1 = 0.f, s2 = 0.f;
    for (int rep = 0; rep < NREP; rep++) {
        s1 += ws[WS_S1 + rep * 1600 + fin];
        s2 += ws[WS_S2 + rep * 1600 + fin];
    }
    const float mean = s1 * (1.f / (NN * TT));
    float var = s2 * (1.f / (NN * TT)) - mean * mean;
    var = fmaxf(var, 0.f);
    const float rs = rsqrtf(var + BN_EPS);
    const float a = gamma[f] * rs;
    const float b = beta[f] - mean * a;
    ((unsigned*)ws)[WS_ABP + f] = (unsigned)f2bf(a) | (((unsigned)f2bf(b)) << 16);
}

// ---------------- K_bn: streaming BN + shift-out + residual + relu ----------------
__global__ __launch_bounds__(256) void k_bn(const float* __restrict__ x0,
                                            const float* __restrict__ ws,
                                            float* __restrict__ out) {
    __shared__ __align__(16) unsigned short ybL[6400];   // 12800 B
    __shared__ float aL[25], bL[25];
    const int d = blockIdx.x, n = blockIdx.y;
    const int tid = threadIdx.x;
    const size_t pbase = (size_t)(n * 64 + d) * 6400;
    const unsigned short* yb = (const unsigned short*)(ws + WS_YB);

    for (int l = tid; l < 800; l += 256)
        *(uint4*)&ybL[l * 8] = *(const uint4*)(yb + pbase + l * 8);
    if (tid < 25) {
        const unsigned u = ((const unsigned*)ws)[WS_ABP + tid * 64 + d];
        aL[tid] = __uint_as_float(u << 16);
        bL[tid] = __uint_as_float(u & 0xffff0000u);
    }
    __syncthreads();

    const int sh = d % 25;
    for (int l4 = tid; l4 < 1600; l4 += 256) {
        const int e0 = 4 * l4;
        const float4 xv = *(const float4*)(x0 + pbase + e0);
        int t = e0 / 25;
        int vo = e0 - 25 * t;
        float o[4];
        const float xe[4] = {xv.x, xv.y, xv.z, xv.w};
#pragma unroll
        for (int k = 0; k < 4; k++) {
            int vs = vo - sh; if (vs < 0) vs += 25;
            const float y = bf2f(ybL[t * 25 + vs]);
            o[k] = fmaxf(fmaf(aL[vo], y, bL[vo]) + xe[k], 0.f);
            vo++; if (vo >= 25) { vo = 0; t++; }
        }
        float4 ov = {o[0], o[1], o[2], o[3]};
        *(float4*)(out + pbase + e0) = ov;
    }
}

extern "C" void kernel_launch(void* const* d_in, const int* in_sizes, int n_in,
                              void* d_out, int out_size, void* d_ws, size_t ws_size,
                              hipStream_t stream) {
    const float* x0    = (const float*)d_in[0];
    const float* fc1_w = (const float*)d_in[1];
    const float* fc1_b = (const float*)d_in[2];
    const float* fc2_w = (const float*)d_in[3];
    const float* fc2_b = (const float*)d_in[4];
    const float* lw    = (const float*)d_in[5];
    const float* lb    = (const float*)d_in[6];
    const float* fmask = (const float*)d_in[7];
    const float* gamma = (const float*)d_in[8];
    const float* beta  = (const float*)d_in[9];
    const int* epoch   = (const int*)d_in[12];
    float* ws  = (float*)d_ws;
    float* out = (float*)d_out;
    unsigned short* xT = (unsigned short*)d_out;     // lower half of d_out; dead before k_bn writes
    const unsigned short* wtb = (const unsigned short*)(ws + WS_WTB);

    // zero pooled + gate/bfuse/mask/abp + stat replicas
    hipMemsetAsync(d_ws, 0, (size_t)WS_WTB * sizeof(float), stream);

    k_mask<<<7, 256, 0, stream>>>(fmask, ws);
    k_xt<<<dim3(64, 64), 256, 0, stream>>>(x0, ws, ws + WS_POOLED, xT);
    k_gate<<<1, 256, 0, stream>>>(fc1_w, fc1_b, fc2_w, fc2_b, lb, epoch, ws);
    k_wfuse<<<NN, 256, 0, stream>>>(lw, ws);
    k_gemm<<<dim3(16, 64), 256, 0, stream>>>(xT, wtb, ws, ws);
    k_finalize<<<7, 256, 0, stream>>>(gamma, beta, ws);
    k_bn<<<dim3(64, 64), 256, 0, stream>>>(x0, ws, out);
}